// Round 2
// baseline (229.022 us; speedup 1.0000x reference)
//
#include <hip/hip_runtime.h>
#include <stdint.h>

#define NN 8192
#define EE 262144
#define DD 128
#define NEGS 0.2f
#define HBITS 20

__device__ __forceinline__ unsigned f2ord(float f){
  unsigned u = __float_as_uint(f);
  return (u & 0x80000000u) ? ~u : (u | 0x80000000u);
}
__device__ __forceinline__ float ord2f(unsigned u){
  return __uint_as_float((u & 0x80000000u) ? (u & 0x7fffffffu) : ~u);
}
__device__ __forceinline__ unsigned hmix(int key){
  unsigned h = (unsigned)key * 2654435761u;
  h ^= h >> 15;
  return h;
}

// ---- clear hash table (keys and vals to -1) ----
__global__ void k_hashclear(int* hkeys, int* hvals){
  int i = blockIdx.x*256 + threadIdx.x;    // int4 index
  int4 m1 = {-1,-1,-1,-1};
  ((int4*)hkeys)[i] = m1;
  ((int4*)hvals)[i] = m1;
}

// ---- init small state (cnt/cursor/T/fillmax) ----
__global__ void k_init(int* cnt, int* cursor, float* T, unsigned* fillmax){
  int i = blockIdx.x*256 + threadIdx.x;
  if(i < NN){ cnt[i] = 0; cursor[i] = 0; }
  if(i < DD) T[i] = 0.f;
  if(i == 0) *fillmax = 0x007FFFFFu;   // f2ord(-inf)
}

// ---- transpose W -> wt[k][c] ----
__global__ void k_wt(const float* __restrict__ W, float* __restrict__ wt){
  int idx = blockIdx.x*256 + threadIdx.x;   // 0..16383
  int c = idx >> 7, k = idx & 127;
  wt[k*DD + c] = W[idx];
}

// ---- h_trans = h @ W^T : block = 16 rows, LDS-tiled f32 ----
__global__ __launch_bounds__(256) void k_gemm(const float* __restrict__ h,
                                              const float* __restrict__ wt,
                                              float* __restrict__ ht){
  __shared__ float wl[64*DD];      // 32KB: half of Wt (64 k-values x 128 cols)
  __shared__ float hl[16][132];    // padded rows
  int t = threadIdx.x;
  int row0 = blockIdx.x * 16;
  #pragma unroll
  for(int u=0;u<2;u++){
    int f4 = u*256 + t;            // float4 index over 16x128
    int r = f4 >> 5, k4 = f4 & 31;
    float4 v = ((const float4*)(h + (size_t)(row0+r)*DD))[k4];
    *((float4*)&hl[r][k4*4]) = v;
  }
  int r  = t >> 4;                 // 0..15
  int c0 = (t & 15) * 8;           // 0..120
  float acc[8];
  #pragma unroll
  for(int s=0;s<8;s++) acc[s]=0.f;
  for(int p=0;p<2;p++){
    __syncthreads();
    const float4* wsrc = (const float4*)(wt + p*64*DD);
    float4* wd = (float4*)wl;
    #pragma unroll
    for(int u=0;u<8;u++) wd[u*256+t] = wsrc[u*256+t];
    __syncthreads();
    #pragma unroll 4
    for(int kk=0;kk<64;kk++){
      float hv = hl[r][p*64+kk];
      const float* wrow = &wl[kk*DD + c0];
      #pragma unroll
      for(int s=0;s<8;s++) acc[s] += hv * wrow[s];
    }
  }
  float4 o0 = {acc[0],acc[1],acc[2],acc[3]};
  float4 o1 = {acc[4],acc[5],acc[6],acc[7]};
  float4* o = (float4*)(ht + (size_t)(row0+r)*DD + c0);
  o[0]=o0; o[1]=o1;
}

// ---- column sum T[d] = sum_i ht[i][d] ----
__global__ void k_colsum(const float* __restrict__ ht, float* T){
  __shared__ float part[256];
  int t = threadIdx.x; int c = t & 127; int half = t >> 7;
  float s = 0.f;
  int r0 = blockIdx.x*128 + half*64;
  for(int r=r0; r<r0+64; r++) s += ht[(size_t)r*DD + c];
  part[t] = s; __syncthreads();
  if(half==0) atomicAdd(&T[c], part[t] + part[t+128]);
}

// ---- per-node a1,a2 (dot with att halves), wave per node ----
__global__ void k_a(const float* __restrict__ ht, const float* __restrict__ att,
                    float* a1, float* a2){
  int lane = threadIdx.x & 63;
  int i = blockIdx.x*4 + (threadIdx.x >> 6);
  const float* hr = ht + (size_t)i*DD;
  float x1 = hr[lane]*att[lane]    + hr[lane+64]*att[lane+64];
  float x2 = hr[lane]*att[DD+lane] + hr[lane+64]*att[DD+lane+64];
  #pragma unroll
  for(int o=32;o>0;o>>=1){ x1 += __shfl_down(x1,o); x2 += __shfl_down(x2,o); }
  if(lane==0){ a1[i]=x1; a2[i]=x2; }
}

// ---- per-edge: value, global max, hash insert (last-write-wins = max k) ----
__global__ void k_edge(const int* __restrict__ ei, const float* __restrict__ a1,
                       const float* __restrict__ a2, float* __restrict__ val,
                       unsigned* fillmax, int* hkeys, int* hvals, int hmask){
  int k = blockIdx.x*256 + threadIdx.x;
  int r = ei[k], c = ei[EE + k];
  float e = a1[r] + a2[c];
  e = e >= 0.f ? e : NEGS*e;
  val[k] = e;
  float wm = e;
  #pragma unroll
  for(int o=32;o>0;o>>=1) wm = fmaxf(wm, __shfl_down(wm,o));
  __shared__ float sm[4];
  if((threadIdx.x & 63)==0) sm[threadIdx.x>>6] = wm;
  __syncthreads();
  if(threadIdx.x==0){
    float bm = fmaxf(fmaxf(sm[0],sm[1]), fmaxf(sm[2],sm[3]));
    atomicMax(fillmax, f2ord(bm));
  }
  if(r != c){
    int key = r*NN + c;                       // < 2^26
    unsigned slot = hmix(key) & hmask;
    while(true){
      int prev = atomicCAS(&hkeys[slot], -1, key);
      if(prev == -1 || prev == key){ atomicMax(&hvals[slot], k); break; }
      slot = (slot + 1) & hmask;
    }
  }
}

// ---- count entries per row (entry i->j, plus j->i when reverse edge absent) ----
__global__ void k_count(const int* __restrict__ hkeys, int* cnt, int hmask){
  int s = blockIdx.x*256 + threadIdx.x;
  int key = hkeys[s];
  if(key < 0) return;
  int i = key >> 13, j = key & (NN-1);
  int rkey = j*NN + i;
  unsigned slot = hmix(rkey) & hmask;
  int found = 0;
  while(true){
    int kk = hkeys[slot];
    if(kk == rkey){ found = 1; break; }
    if(kk == -1) break;
    slot = (slot + 1) & hmask;
  }
  atomicAdd(&cnt[i], 1);
  if(!found) atomicAdd(&cnt[j], 1);
}

// ---- exclusive scan of cnt (8192) -> rowstart ----
__global__ void k_scan(const int* __restrict__ cnt, int* rowstart){
  __shared__ int part[1024];
  int t = threadIdx.x;
  int loc[8]; int s = 0;
  #pragma unroll
  for(int u=0;u<8;u++){ loc[u]=s; s += cnt[t*8+u]; }
  part[t] = s; __syncthreads();
  for(int o=1;o<1024;o<<=1){
    int add = (t>=o) ? part[t-o] : 0;
    __syncthreads();
    part[t] += add;
    __syncthreads();
  }
  int pre = part[t] - s;
  #pragma unroll
  for(int u=0;u<8;u++) rowstart[t*8+u] = pre + loc[u];
  if(t==1023) rowstart[NN] = part[1023];
}

// ---- fill CSR entries: (col, symmetrized value) ----
__global__ void k_fill(const int* __restrict__ hkeys, const int* __restrict__ hvals,
                       const float* __restrict__ val, const int* __restrict__ rowstart,
                       int* cursor, int* __restrict__ ecol, float* __restrict__ eval,
                       int hmask){
  int s = blockIdx.x*256 + threadIdx.x;
  int key = hkeys[s];
  if(key < 0) return;
  int i = key >> 13, j = key & (NN-1);
  int kwin = hvals[s];
  int rkey = j*NN + i;
  unsigned slot = hmix(rkey) & hmask;
  int krev = -1;
  while(true){
    int kk = hkeys[slot];
    if(kk == rkey){ krev = hvals[slot]; break; }
    if(kk == -1) break;
    slot = (slot + 1) & hmask;
  }
  float a = 0.5f * (val[kwin] + (krev >= 0 ? val[krev] : 0.f));
  int p = rowstart[i] + atomicAdd(&cursor[i], 1);
  ecol[p] = j; eval[p] = a;
  if(krev < 0){
    int q = rowstart[j] + atomicAdd(&cursor[j], 1);
    ecol[q] = i; eval[q] = a;
  }
}

// ---- per-row: softmax stats + h_prime (sparse), wave per row ----
__global__ __launch_bounds__(256) void k_row(const float* __restrict__ ht,
    const float* __restrict__ T, const int* __restrict__ rowst,
    const int* __restrict__ cnt, const int* __restrict__ ecol,
    const float* __restrict__ eval, const unsigned* __restrict__ fillmax,
    float* m_, float* inv_, float* z_, float* dg_, float* __restrict__ hprime){
  int lane = threadIdx.x & 63;
  int i = blockIdx.x*4 + (threadIdx.x >> 6);
  float fill = ord2f(*fillmax);
  int st = rowst[i], n = cnt[i];
  float mx = -INFINITY;
  for(int e=lane; e<n; e+=64) mx = fmaxf(mx, eval[st+e]);
  #pragma unroll
  for(int o=32;o>0;o>>=1) mx = fmaxf(mx, __shfl_xor(mx, o));
  float m = fmaxf(fill, mx);
  if(n < NN-1) m = fmaxf(m, 0.f);       // unset cells are zeros
  float dsum = 0.f;
  for(int e=lane; e<n; e+=64) dsum += __expf(eval[st+e]-m);
  #pragma unroll
  for(int o=32;o>0;o>>=1) dsum += __shfl_xor(dsum, o);
  float ez = __expf(-m);
  float ef = __expf(fill-m);
  float denom = dsum + ef + (float)(NN-1-n)*ez;
  float invd = 1.f/denom;
  if(lane==0){ m_[i]=m; inv_[i]=invd; z_[i]=ez*invd; dg_[i]=ef*invd; }
  const float* hti = ht + (size_t)i*DD;
  float acc0 = ez*T[lane]    + (ef-ez)*hti[lane];
  float acc1 = ez*T[lane+64] + (ef-ez)*hti[lane+64];
  for(int e=0;e<n;e++){
    int j = ecol[st+e];
    float w = __expf(eval[st+e]-m) - ez;
    const float* htj = ht + (size_t)j*DD;
    acc0 += w*htj[lane];
    acc1 += w*htj[lane+64];
  }
  acc0 *= invd; acc1 *= invd;
  acc0 = acc0 > 0.f ? acc0 : expm1f(acc0);   // ELU
  acc1 = acc1 > 0.f ? acc1 : expm1f(acc1);
  hprime[(size_t)i*DD + lane]      = acc0;
  hprime[(size_t)i*DD + lane + 64] = acc1;
}

// ---- dense attention write: build row in LDS, stream out ----
__global__ __launch_bounds__(256) void k_dense(const int* __restrict__ rowst,
    const int* __restrict__ cnt, const int* __restrict__ ecol,
    const float* __restrict__ eval, const float* __restrict__ m_,
    const float* __restrict__ inv_, const float* __restrict__ z_,
    const float* __restrict__ dg_, float* __restrict__ attn){
  __shared__ float rowbuf[NN];     // 32KB
  int i = blockIdx.x, t = threadIdx.x;
  float z = z_[i], m = m_[i], inv = inv_[i];
  float4 zv = {z,z,z,z};
  float4* rb4 = (float4*)rowbuf;
  #pragma unroll
  for(int u=0;u<8;u++) rb4[u*256+t] = zv;
  __syncthreads();
  int st = rowst[i], n = cnt[i];
  for(int e=t; e<n; e+=256)
    rowbuf[ecol[st+e]] = __expf(eval[st+e]-m)*inv;
  if(t==0) rowbuf[i] = dg_[i];
  __syncthreads();
  float4* o = (float4*)(attn + (size_t)i*NN);
  #pragma unroll
  for(int u=0;u<8;u++) o[u*256+t] = rb4[u*256+t];
}

extern "C" void kernel_launch(void* const* d_in, const int* in_sizes, int n_in,
                              void* d_out, int out_size, void* d_ws, size_t ws_size,
                              hipStream_t stream){
  const float* h   = (const float*)d_in[0];
  const int*   ei  = (const int*)d_in[1];     // harness passes integers as int32
  const float* W   = (const float*)d_in[2];
  const float* att = (const float*)d_in[3];
  float* out = (float*)d_out;
  float* hprime = out;                       // [N, D]
  float* attn   = out + (size_t)NN*DD;       // [N, N]

  // Large early-phase scratch lives inside the dense-attention output region
  // (dead until k_dense, which rewrites all of it last).
  const int hsize = 1 << HBITS, hmask = hsize - 1;
  int*   hkeys = (int*)attn;                     // 4 MB
  int*   hvals = hkeys + hsize;                  // 4 MB
  float* ht    = (float*)(hvals + hsize);        // 4 MB
  float* val   = ht + (size_t)NN*DD;             // 1 MB
  float* wt    = val + EE;                       // 64 KB
  float* a1    = wt + DD*DD;                     // 32 KB
  float* a2    = a1 + NN;                        // 32 KB

  // d_ws holds only what k_dense itself consumes (~4.4 MB).
  char* ws = (char*)d_ws;
  size_t off = 0;
  auto alloc = [&](size_t bytes)->char*{
    char* p = ws + off;
    off = (off + bytes + 15) & ~(size_t)15;
    return p;
  };
  int*   ecol   = (int*)alloc((size_t)2*EE*4);   // 2 MB
  float* eval   = (float*)alloc((size_t)2*EE*4); // 2 MB
  float* T      = (float*)alloc((size_t)DD*4);
  float* m_     = (float*)alloc((size_t)NN*4);
  float* inv_   = (float*)alloc((size_t)NN*4);
  float* z_     = (float*)alloc((size_t)NN*4);
  float* dg_    = (float*)alloc((size_t)NN*4);
  int*   cnt    = (int*)alloc((size_t)NN*4);
  int*   rowst  = (int*)alloc((size_t)(NN+1)*4);
  int*   cursor = (int*)alloc((size_t)NN*4);
  unsigned* fillmax = (unsigned*)alloc(16);

  k_hashclear<<<hsize/(256*4), 256, 0, stream>>>(hkeys, hvals);
  k_init  <<<32, 256, 0, stream>>>(cnt, cursor, T, fillmax);
  k_wt    <<<64, 256, 0, stream>>>(W, wt);
  k_gemm  <<<NN/16, 256, 0, stream>>>(h, wt, ht);
  k_colsum<<<64, 256, 0, stream>>>(ht, T);
  k_a     <<<NN/4, 256, 0, stream>>>(ht, att, a1, a2);
  k_edge  <<<EE/256, 256, 0, stream>>>(ei, a1, a2, val, fillmax, hkeys, hvals, hmask);
  k_count <<<hsize/256, 256, 0, stream>>>(hkeys, cnt, hmask);
  k_scan  <<<1, 1024, 0, stream>>>(cnt, rowst);
  k_fill  <<<hsize/256, 256, 0, stream>>>(hkeys, hvals, val, rowst, cursor, ecol, eval, hmask);
  k_row   <<<NN/4, 256, 0, stream>>>(ht, T, rowst, cnt, ecol, eval, fillmax, m_, inv_, z_, dg_, hprime);
  k_dense <<<NN, 256, 0, stream>>>(rowst, cnt, ecol, eval, m_, inv_, z_, dg_, attn);
}